// Round 11
// baseline (342.580 us; speedup 1.0000x reference)
//
#include <hip/hip_runtime.h>

#define T_SEQ 512
#define INPUT 14
#define HID 8
#define TC 16
#define NCHUNK (T_SEQ / TC)
#define BN_EPS 1e-5f

typedef float v2f __attribute__((ext_vector_type(2)));

__device__ __forceinline__ float fast_exp2(float x) { return __builtin_amdgcn_exp2f(x); }
__device__ __forceinline__ float fast_rcp(float x)  { return __builtin_amdgcn_rcpf(x); }

// packed fp32 math (CDNA): one instruction, two FMAs per lane
__device__ __forceinline__ v2f pk_fma(v2f a, v2f b, v2f c) {
    v2f d;
    asm("v_pk_fma_f32 %0, %1, %2, %3" : "=v"(d) : "v"(a), "v"(b), "v"(c));
    return d;
}
__device__ __forceinline__ v2f pk_mul(v2f a, v2f b) {
    v2f d;
    asm("v_pk_mul_f32 %0, %1, %2" : "=v"(d) : "v"(a), "v"(b));
    return d;
}
__device__ __forceinline__ v2f pk_add(v2f a, v2f b) {
    v2f d;
    asm("v_pk_add_f32 %0, %1, %2" : "=v"(d) : "v"(a), "v"(b));
    return d;
}

// ds_swizzle fallback (BitMode imm = xor<<10 | or<<5 | and)
template <int IMM>
__device__ __forceinline__ float swz(float v) {
    return __int_as_float(__builtin_amdgcn_ds_swizzle(__float_as_int(v), IMM));
}

// DPP cross-lane ops (VALU pipe)
#define DPP_BC0   0x00   // quad_perm [0,0,0,0] : broadcast quad-lane 0 (gate i)
#define DPP_BC1   0x55   // quad_perm [1,1,1,1] : broadcast quad-lane 1 (gate f)
#define DPP_BC2   0xAA   // quad_perm [2,2,2,2] : broadcast quad-lane 2 (gate g)
#define DPP_BC3   0xFF   // quad_perm [3,3,3,3] : broadcast quad-lane 3 (gate o)
#define DPP_ROR4  0x124  // row rotate 4 within 16-row (direction probed at init)
#define DPP_ROR8  0x128  // row rotate 8 = lane ^= 8 (direction-symmetric)
#define DPP_ROR12 0x12C  // row rotate 12
template <int CTRL>
__device__ __forceinline__ float dpp(float v) {
    return __int_as_float(__builtin_amdgcn_update_dpp(
        0, __float_as_int(v), CTRL, 0xF, 0xF, true));
}
template <int CTRL>
__device__ __forceinline__ int dpp_i(int v) {
    return __builtin_amdgcn_update_dpp(0, v, CTRL, 0xF, 0xF, true);
}

// lane^16 on the VALU pipe -- R7-PROVEN XOR-identity form (absmax 0.0 in R7):
// permlane16_swap with both operands = h yields {own, lane^16} per lane in SOME
// order under any output convention, so r0 ^ r1 ^ h = h[lane^16] regardless.
// Fallback: LDS swizzle (proven since R2).
__device__ __forceinline__ float xor16v(float h) {
#if __has_builtin(__builtin_amdgcn_permlane16_swap)
    unsigned hb = __float_as_uint(h);
    auto r = __builtin_amdgcn_permlane16_swap(hb, hb, false, false);
    return __uint_as_float(r[0] ^ r[1] ^ hb);
#else
    return swz<0x401F>(h);
#endif
}

// ============================================================================
// DS-FREE BUTTERFLY producing EXACTLY R8's image pairs (weight layout untouched):
//   hx[0]={h, x8}, hx[1]={x4, x12}, hx[2]={x16, x24}, hx[3]={x20, x28}
// Unit-major layout (lane = u*4 + type): lane^4 / lane^12 flip row-local bits
// {2} / {2,3}, which equal the ror4/ror12 rotation images SELECTED by lane bit 2:
//   x4  = bit2 ? img(src i+12) : img(src i+4)     (verified lanes 0/4/8/12)
//   x12 = bit2 ? img(src i+4)  : img(src i+12)
// selB (precomputed, loop-invariant) folds the ror-direction probe into the
// select: selB = (bit2 == dplus) -> x4 = selB ? rB : rA.  lane^8 = ror8
// (direction-symmetric); lane^16 = xor16v (R7-proven); x20/x24/x28 = the same
// ops applied to hs = h[lane^16].  6 dpp + 1 permlane + 2 xor + 4 cndmask,
// ZERO DS ops -- removes the 6 chain-critical ds_swizzle LDS round-trips.
// ============================================================================
__device__ __forceinline__ void butterfly8x(float h, v2f (&hx)[4], bool selB) {
    float rA  = dpp<DPP_ROR4>(h);
    float rB  = dpp<DPP_ROR12>(h);
    float x8  = dpp<DPP_ROR8>(h);
    float hs  = xor16v(h);
    float x4  = selB ? rB : rA;
    float x12 = selB ? rA : rB;
    float sA  = dpp<DPP_ROR4>(hs);
    float sB  = dpp<DPP_ROR12>(hs);
    float x24 = dpp<DPP_ROR8>(hs);
    float x20 = selB ? sB : sA;
    float x28 = selB ? sA : sB;
    hx[0].x = h;   hx[0].y = x8;
    hx[1].x = x4;  hx[1].y = x12;
    hx[2].x = hs;  hx[2].y = x24;
    hx[3].x = x20; hx[3].y = x28;
}

// ============================================================================
// TIME-SKEWED TWO-LAYER SCHEDULE (R8, passed absmax 0.0) + DS-free butterfly.
// Block: 256 threads = 4 waves; each wave = 2 batch elements (32 lanes each).
// Within 32 lanes: unit = (l5>>2)&7, type = l5&3 (0=i,1=f,2=g,3=o).
// Body s computes L1(t=s) and L2(t=s-1) (independent act chains).
// Numerics: weights/biases pre-scaled by the lane's exp2 activation constant;
// cell state kept pre-scaled (C = -2.885*c) so tanh(c)=2*rcp(1+exp2(C))-1.
// ============================================================================
__global__ __launch_bounds__(256, 2)
void lstm_forex_kernel(const float* __restrict__ x,
                       const float* __restrict__ Wih1, const float* __restrict__ Whh1,
                       const float* __restrict__ bih1, const float* __restrict__ bhh1,
                       const float* __restrict__ Wih2, const float* __restrict__ Whh2,
                       const float* __restrict__ bih2, const float* __restrict__ bhh2,
                       const float* __restrict__ bn_gamma, const float* __restrict__ bn_beta,
                       const float* __restrict__ bn_mean, const float* __restrict__ bn_var,
                       const float* __restrict__ w1p, const float* __restrict__ b1p,
                       const float* __restrict__ w2p, const float* __restrict__ b2p,
                       float* __restrict__ out)
{
    __shared__ float xbuf[4][2][TC][16];   // [wave][elem][t][14 padded to 16]

    const int tid  = threadIdx.x;
    const int wave = tid >> 6;
    const int lane = tid & 63;
    const int grp  = lane >> 5;          // which of the wave's 2 batch elements
    const int l5   = lane & 31;
    const int u    = (l5 >> 2) & 7;      // unit
    const int type = l5 & 3;             // gate type
    const int row  = type * 8 + u;       // weight row (PyTorch i,f,g,o blocks)

    const int b = blockIdx.x * 8 + wave * 2 + grp;

    // ---- ror4 direction probe (once; R7-proven): dst i = src (i+4)&15 => dplus
    const int got = dpp_i<DPP_ROR4>(l5);
    const bool dplus = (got == ((l5 & 16) | ((l5 + 4) & 15)));
    const bool bit2  = ((l5 >> 2) & 1) != 0;
    const bool selB  = (bit2 == dplus);  // x4 = selB ? ror12img : ror4img

    // exp2-domain activation constants; scale folded into weights below
    const float gateScale = (type == 2) ? -2.885390082f : -1.4426950408f;
    const float actMul    = (type == 2) ? -5.770780164f : 1.f;   // g-lane -> -2.885*tanh(g)
    const float actAdd    = (type == 2) ?  2.885390082f : 0.f;

    // ---- per-lane weight rows (pre-scaled); recurrent mats pre-permuted for XOR
    //      butterfly, paired to the image pairs {0,2},{1,3},{4,6},{5,7} (R8 layout) ----
    v2f wi1p[7], wh1v[4], wi2v[4], wh2v[4];
#pragma unroll
    for (int k = 0; k < 7; ++k) {
        wi1p[k].x = Wih1[row * INPUT + 2 * k]     * gateScale;
        wi1p[k].y = Wih1[row * INPUT + 2 * k + 1] * gateScale;
    }
    const int poff[4] = {0, 1, 4, 5};
#pragma unroll
    for (int p = 0; p < 4; ++p) {
        int j0 = u ^ poff[p], j1 = j0 ^ 2;
        wh1v[p].x = Whh1[row * HID + j0] * gateScale;
        wh1v[p].y = Whh1[row * HID + j1] * gateScale;
        wi2v[p].x = Wih2[row * HID + j0] * gateScale;
        wi2v[p].y = Wih2[row * HID + j1] * gateScale;
        wh2v[p].x = Whh2[row * HID + j0] * gateScale;
        wh2v[p].y = Whh2[row * HID + j1] * gateScale;
    }
    const float bsum1s = (bih1[row] + bhh1[row]) * gateScale;
    const float bsum2s = (bih2[row] + bhh2[row]) * gateScale;
    const v2f   bias1  = { bsum1s, 0.f };
    const v2f   bias2  = { bsum2s, 0.f };

    // ---- x staging: 448 dwords per wave-chunk (2 elems * 16 t * 14), 7 per lane ----
    const float* gptr[7];
    int loff[7];
#pragma unroll
    for (int it = 0; it < 7; ++it) {
        int d   = it * 64 + lane;       // coalesced flat dword index within wave-chunk
        int es  = d / 224;              // which elem
        int idx = d - es * 224;         // dword within elem's 16x14 chunk
        int tr  = idx / 14;
        int k   = idx - tr * 14;
        int bb  = blockIdx.x * 8 + wave * 2 + es;
        gptr[it] = x + (size_t)bb * (T_SEQ * INPUT) + idx;
        loff[it] = es * (TC * 16) + tr * 16 + k;   // padded LDS layout
    }

    v2f hx1[4], hx2[4];                 // paired butterfly images of h1, h2
    float c1 = 0.f, c2 = 0.f;           // PRE-SCALED cell states (C = -2.885*c)
#pragma unroll
    for (int p = 0; p < 4; ++p) { hx1[p] = (v2f){0.f, 0.f}; hx2[p] = (v2f){0.f, 0.f}; }

    // prefetch chunk 0
    float st[7];
#pragma unroll
    for (int it = 0; it < 7; ++it) { st[it] = *gptr[it]; gptr[it] += TC * INPUT; }

    float (*xw)[TC][16] = xbuf[wave];

    for (int c = 0; c < NCHUNK; ++c) {
        // stage chunk c into LDS (in-order DS per wave makes this visible below)
#pragma unroll
        for (int it = 0; it < 7; ++it) ((float*)xw)[loff[it]] = st[it];
        // prefetch chunk c+1 while computing chunk c
        if (c + 1 < NCHUNK) {
#pragma unroll
            for (int it = 0; it < 7; ++it) { st[it] = *gptr[it]; gptr[it] += TC * INPUT; }
        }
        __builtin_amdgcn_wave_barrier();

        // ===== Phase A: batched x-projections for all 16 steps -> registers =====
        v2f xp0[TC], xp1[TC];
#pragma unroll
        for (int t = 0; t < TC; ++t) {
            const float* xrow = &xw[grp][t][0];
            float4 xa = *(const float4*)(xrow + 0);
            float4 xb = *(const float4*)(xrow + 4);
            float4 xc = *(const float4*)(xrow + 8);
            float2 xd = *(const float2*)(xrow + 12);
            v2f a0 = pk_fma((v2f){xa.x, xa.y}, wi1p[0], bias1);
            v2f a1 = pk_mul((v2f){xa.z, xa.w}, wi1p[1]);
            a0 = pk_fma((v2f){xb.x, xb.y}, wi1p[2], a0);
            a1 = pk_fma((v2f){xb.z, xb.w}, wi1p[3], a1);
            a0 = pk_fma((v2f){xc.x, xc.y}, wi1p[4], a0);
            a1 = pk_fma((v2f){xc.z, xc.w}, wi1p[5], a1);
            a0 = pk_fma((v2f){xd.x, xd.y}, wi1p[6], a0);
            xp0[t] = a0;
            xp1[t] = a1;
        }

        // ===== Phase B: skewed recurrence -- body s computes L1(s) and L2(s-1) =====
#pragma unroll
        for (int t = 0; t < TC; ++t) {
            // ---- L1 dot for step s (uses hx1 = h1(s-1) images) ----
            v2f sA = pk_fma(hx1[0], wh1v[0], xp0[t]);
            v2f sB = pk_fma(hx1[1], wh1v[1], xp1[t]);
            sA = pk_fma(hx1[2], wh1v[2], sA);
            sB = pk_fma(hx1[3], wh1v[3], sB);
            v2f sC = pk_add(sA, sB);
            float acc1 = sC.x + sC.y;

            // ---- L2 dot for step s-1 (hx2 = h2(s-2) images; hx1 read before
            //      butterfly1 overwrites them) ----
            v2f qA = pk_fma(hx2[0], wh2v[0], bias2);
            v2f qB = pk_mul(hx2[1], wh2v[1]);
            qA = pk_fma(hx2[2], wh2v[2], qA);
            qB = pk_fma(hx2[3], wh2v[3], qB);
            v2f pA = pk_fma(hx1[0], wi2v[0], qA);
            v2f pB = pk_fma(hx1[1], wi2v[1], qB);
            pA = pk_fma(hx1[2], wi2v[2], pA);
            pB = pk_fma(hx1[3], wi2v[3], pB);
            v2f pC = pk_add(pA, pB);
            float acc2 = pC.x + pC.y;

            // ---- two INDEPENDENT activation chains (compiler interleaves) ----
            float v0 = fmaf(fast_rcp(1.f + fast_exp2(acc1)), actMul, actAdd);
            float u0 = fmaf(fast_rcp(1.f + fast_exp2(acc2)), actMul, actAdd);

            float vi = dpp<DPP_BC0>(v0);
            float vf = dpp<DPP_BC1>(v0);
            float vg = dpp<DPP_BC2>(v0);   // = -2.885*tanh(g)
            float vo = dpp<DPP_BC3>(v0);
            c1 = fmaf(vf, c1, vi * vg);
            float th1 = fmaf(fast_rcp(1.f + fast_exp2(c1)), 2.f, -1.f);
            float h1u = vo * th1;          // h1(s)

            float ui = dpp<DPP_BC0>(u0);
            float uf = dpp<DPP_BC1>(u0);
            float ug = dpp<DPP_BC2>(u0);
            float uo = dpp<DPP_BC3>(u0);
            c2 = fmaf(uf, c2, ui * ug);
            float th2 = fmaf(fast_rcp(1.f + fast_exp2(c2)), 2.f, -1.f);
            float h2u = uo * th2;          // h2(s-1)

            butterfly8x(h1u, hx1, selB);
            butterfly8x(h2u, hx2, selB);

            // first body's L2 output is garbage (h2(-1) must be 0)
            if (c == 0 && t == 0) {
#pragma unroll
                for (int p = 0; p < 4; ++p) hx2[p] = (v2f){0.f, 0.f};
                c2 = 0.f;
            }
        }
    }

    // ---- epilogue drain: L2 for t=511 (hx1 = h1(511), hx2 = h2(510)) ----
    {
        v2f qA = pk_fma(hx2[0], wh2v[0], bias2);
        v2f qB = pk_mul(hx2[1], wh2v[1]);
        qA = pk_fma(hx2[2], wh2v[2], qA);
        qB = pk_fma(hx2[3], wh2v[3], qB);
        v2f pA = pk_fma(hx1[0], wi2v[0], qA);
        v2f pB = pk_fma(hx1[1], wi2v[1], qB);
        pA = pk_fma(hx1[2], wi2v[2], pA);
        pB = pk_fma(hx1[3], wi2v[3], pB);
        v2f pC = pk_add(pA, pB);
        float acc2 = pC.x + pC.y;

        float u0 = fmaf(fast_rcp(1.f + fast_exp2(acc2)), actMul, actAdd);
        float ui = dpp<DPP_BC0>(u0);
        float uf = dpp<DPP_BC1>(u0);
        float ug = dpp<DPP_BC2>(u0);
        float uo = dpp<DPP_BC3>(u0);
        c2 = fmaf(uf, c2, ui * ug);
        float th2 = fmaf(fast_rcp(1.f + fast_exp2(c2)), 2.f, -1.f);
        float h2u = uo * th2;              // h2(511)
        butterfly8x(h2u, hx2, selB);
    }

    // ---- BN (eval) + MLP head, one lane per batch element ----
    // At l5==0 (u==0): pairs hold units {0,2},{1,3},{4,6},{5,7}  (R8 layout).
    if (l5 == 0) {
        float h2v[HID];
        h2v[0] = hx2[0].x; h2v[2] = hx2[0].y;
        h2v[1] = hx2[1].x; h2v[3] = hx2[1].y;
        h2v[4] = hx2[2].x; h2v[6] = hx2[2].y;
        h2v[5] = hx2[3].x; h2v[7] = hx2[3].y;
        float nd[HID];
#pragma unroll
        for (int j = 0; j < HID; ++j) {
            float inv = 1.f / sqrtf(bn_var[j] + BN_EPS);
            nd[j] = bn_gamma[j] * (h2v[j] - bn_mean[j]) * inv + bn_beta[j];
        }
        float acc = b2p[0];
#pragma unroll
        for (int m = 0; m < 4; ++m) {
            float s = b1p[m];
#pragma unroll
            for (int j = 0; j < HID; ++j) s = fmaf(nd[j], w1p[m * HID + j], s);
            s = fmaxf(s, 0.f);
            acc = fmaf(s, w2p[m], acc);
        }
        out[b] = acc;
    }
}

extern "C" void kernel_launch(void* const* d_in, const int* in_sizes, int n_in,
                              void* d_out, int out_size, void* d_ws, size_t ws_size,
                              hipStream_t stream) {
    const float* x        = (const float*)d_in[0];
    const float* Wih1     = (const float*)d_in[1];
    const float* Whh1     = (const float*)d_in[2];
    const float* bih1     = (const float*)d_in[3];
    const float* bhh1     = (const float*)d_in[4];
    const float* Wih2     = (const float*)d_in[5];
    const float* Whh2     = (const float*)d_in[6];
    const float* bih2     = (const float*)d_in[7];
    const float* bhh2     = (const float*)d_in[8];
    const float* bn_gamma = (const float*)d_in[9];
    const float* bn_beta  = (const float*)d_in[10];
    const float* bn_mean  = (const float*)d_in[11];
    const float* bn_var   = (const float*)d_in[12];
    const float* w1p      = (const float*)d_in[13];
    const float* b1p      = (const float*)d_in[14];
    const float* w2p      = (const float*)d_in[15];
    const float* b2p      = (const float*)d_in[16];
    float* out = (float*)d_out;

    const int B = in_sizes[0] / (T_SEQ * INPUT);   // 4096
    dim3 grid(B / 8), block(256);
    hipLaunchKernelGGL(lstm_forex_kernel, grid, block, 0, stream,
                       x, Wih1, Whh1, bih1, bhh1, Wih2, Whh2, bih2, bhh2,
                       bn_gamma, bn_beta, bn_mean, bn_var, w1p, b1p, w2p, b2p, out);
}

// Round 12
// 311.149 us; speedup vs baseline: 1.1010x; 1.1010x over previous
//
#include <hip/hip_runtime.h>

#define T_SEQ 512
#define INPUT 14
#define HID 8
#define TC 16
#define NCHUNK (T_SEQ / TC)
#define BN_EPS 1e-5f

typedef float v2f __attribute__((ext_vector_type(2)));

__device__ __forceinline__ float fast_exp2(float x) { return __builtin_amdgcn_exp2f(x); }
__device__ __forceinline__ float fast_rcp(float x)  { return __builtin_amdgcn_rcpf(x); }

// packed fp32 math (CDNA): one instruction, two FMAs per lane
__device__ __forceinline__ v2f pk_fma(v2f a, v2f b, v2f c) {
    v2f d;
    asm("v_pk_fma_f32 %0, %1, %2, %3" : "=v"(d) : "v"(a), "v"(b), "v"(c));
    return d;
}
__device__ __forceinline__ v2f pk_mul(v2f a, v2f b) {
    v2f d;
    asm("v_pk_mul_f32 %0, %1, %2" : "=v"(d) : "v"(a), "v"(b));
    return d;
}
__device__ __forceinline__ v2f pk_add(v2f a, v2f b) {
    v2f d;
    asm("v_pk_add_f32 %0, %1, %2" : "=v"(d) : "v"(a), "v"(b));
    return d;
}

// ds_swizzle (LDS crossbar): BitMode imm = xor<<10 | or<<5 | and
template <int IMM>
__device__ __forceinline__ float swz(float v) {
    return __int_as_float(__builtin_amdgcn_ds_swizzle(__float_as_int(v), IMM));
}

// DPP cross-lane ops (VALU pipe)
#define DPP_BC0  0x00   // quad_perm [0,0,0,0] : broadcast quad-lane 0 (gate i)
#define DPP_BC1  0x55   // quad_perm [1,1,1,1] : broadcast quad-lane 1 (gate f)
#define DPP_BC2  0xAA   // quad_perm [2,2,2,2] : broadcast quad-lane 2 (gate g)
#define DPP_BC3  0xFF   // quad_perm [3,3,3,3] : broadcast quad-lane 3 (gate o)
#define DPP_XOR8 0x128  // row_ror:8 : lane ^= 8 within 16-row
template <int CTRL>
__device__ __forceinline__ float dpp(float v) {
    return __int_as_float(__builtin_amdgcn_update_dpp(
        0, __float_as_int(v), CTRL, 0xF, 0xF, true));
}

// UNIT-MAJOR layout: lane(within 32) = unit*4 + type.
// Butterfly images of h over unit bits (lane bits 2..4), paired {h,x8},{x4,x12},
// {x16,x24},{x20,x28}: pair units are u^{0,2},{1,3},{4,6},{5,7}.
__device__ __forceinline__ void butterfly8v(float h, v2f (&hx)[4]) {
    float x8  = dpp<DPP_XOR8>(h);  // xor 8  (VALU)
    float x4  = swz<0x101F>(h);    // xor 4  (LDS crossbar)
    float x16 = swz<0x401F>(h);    // xor 16
    float x20 = swz<0x501F>(h);    // xor 20
    hx[0].x = h;   hx[0].y = x8;
    hx[1].x = x4;  hx[1].y = dpp<DPP_XOR8>(x4);   // xor 12
    hx[2].x = x16; hx[2].y = dpp<DPP_XOR8>(x16);  // xor 24
    hx[3].x = x20; hx[3].y = dpp<DPP_XOR8>(x20);  // xor 28
}

// ============================================================================
// FINAL KERNEL (session best, R8): TIME-SKEWED TWO-LAYER SCHEDULE.
// Block: 256 threads = 4 waves; each wave = 2 batch elements (32 lanes each).
// Within 32 lanes: unit = (l5>>2)&7, type = l5&3 (0=i,1=f,2=g,3=o).
// Per wave-step s the body computes L1(t=s) AND L2(t=s-1): both gate dots are
// ready at body start and the two activation chains are independent.
// Numerics: weights/biases pre-scaled by the lane's exp2 activation constant;
// cell state kept pre-scaled (C = -2.885*c) so tanh(c)=2*rcp(1+exp2(C))-1.
//
// Structural plateau notes (rocprof-backed, rounds 0-11):
//   wall = per-wave issue (~286 cy/step) + serial chain stall (~580 cy/step);
//   occupancy capped at 2 waves/SIMD (4096 elem x 32 lanes / 1024 SIMDs);
//   instruction cuts convert ~1:1 (R1->R2); schedule reorders neutral (R3,R8);
//   64-lane layouts double issue/elem (R4/R6 regress); DS-free butterfly adds
//   more issue than it saves in stall (R11 regress).
// ============================================================================
__global__ __launch_bounds__(256, 2)
void lstm_forex_kernel(const float* __restrict__ x,
                       const float* __restrict__ Wih1, const float* __restrict__ Whh1,
                       const float* __restrict__ bih1, const float* __restrict__ bhh1,
                       const float* __restrict__ Wih2, const float* __restrict__ Whh2,
                       const float* __restrict__ bih2, const float* __restrict__ bhh2,
                       const float* __restrict__ bn_gamma, const float* __restrict__ bn_beta,
                       const float* __restrict__ bn_mean, const float* __restrict__ bn_var,
                       const float* __restrict__ w1p, const float* __restrict__ b1p,
                       const float* __restrict__ w2p, const float* __restrict__ b2p,
                       float* __restrict__ out)
{
    __shared__ float xbuf[4][2][TC][16];   // [wave][elem][t][14 padded to 16]

    const int tid  = threadIdx.x;
    const int wave = tid >> 6;
    const int lane = tid & 63;
    const int grp  = lane >> 5;          // which of the wave's 2 batch elements
    const int l5   = lane & 31;
    const int u    = (l5 >> 2) & 7;      // unit
    const int type = l5 & 3;             // gate type
    const int row  = type * 8 + u;       // weight row (PyTorch i,f,g,o blocks)

    const int b = blockIdx.x * 8 + wave * 2 + grp;

    // exp2-domain activation constants; scale folded into weights below
    const float gateScale = (type == 2) ? -2.885390082f : -1.4426950408f;
    const float actMul    = (type == 2) ? -5.770780164f : 1.f;   // g-lane -> -2.885*tanh(g)
    const float actAdd    = (type == 2) ?  2.885390082f : 0.f;

    // ---- per-lane weight rows (pre-scaled); recurrent mats pre-permuted for XOR
    //      butterfly, paired to match the image pairs {0,2},{1,3},{4,6},{5,7} ----
    v2f wi1p[7], wh1v[4], wi2v[4], wh2v[4];
#pragma unroll
    for (int k = 0; k < 7; ++k) {
        wi1p[k].x = Wih1[row * INPUT + 2 * k]     * gateScale;
        wi1p[k].y = Wih1[row * INPUT + 2 * k + 1] * gateScale;
    }
    const int poff[4] = {0, 1, 4, 5};
#pragma unroll
    for (int p = 0; p < 4; ++p) {
        int j0 = u ^ poff[p], j1 = j0 ^ 2;
        wh1v[p].x = Whh1[row * HID + j0] * gateScale;
        wh1v[p].y = Whh1[row * HID + j1] * gateScale;
        wi2v[p].x = Wih2[row * HID + j0] * gateScale;
        wi2v[p].y = Wih2[row * HID + j1] * gateScale;
        wh2v[p].x = Whh2[row * HID + j0] * gateScale;
        wh2v[p].y = Whh2[row * HID + j1] * gateScale;
    }
    const float bsum1s = (bih1[row] + bhh1[row]) * gateScale;
    const float bsum2s = (bih2[row] + bhh2[row]) * gateScale;
    const v2f   bias1  = { bsum1s, 0.f };
    const v2f   bias2  = { bsum2s, 0.f };

    // ---- x staging: 448 dwords per wave-chunk (2 elems * 16 t * 14), 7 per lane ----
    const float* gptr[7];
    int loff[7];
#pragma unroll
    for (int it = 0; it < 7; ++it) {
        int d   = it * 64 + lane;       // coalesced flat dword index within wave-chunk
        int es  = d / 224;              // which elem
        int idx = d - es * 224;         // dword within elem's 16x14 chunk
        int tr  = idx / 14;
        int k   = idx - tr * 14;
        int bb  = blockIdx.x * 8 + wave * 2 + es;
        gptr[it] = x + (size_t)bb * (T_SEQ * INPUT) + idx;
        loff[it] = es * (TC * 16) + tr * 16 + k;   // padded LDS layout
    }

    v2f hx1[4], hx2[4];                 // paired butterfly images of h1, h2
    float c1 = 0.f, c2 = 0.f;           // PRE-SCALED cell states (C = -2.885*c)
#pragma unroll
    for (int p = 0; p < 4; ++p) { hx1[p] = (v2f){0.f, 0.f}; hx2[p] = (v2f){0.f, 0.f}; }

    // prefetch chunk 0
    float st[7];
#pragma unroll
    for (int it = 0; it < 7; ++it) { st[it] = *gptr[it]; gptr[it] += TC * INPUT; }

    float (*xw)[TC][16] = xbuf[wave];

    for (int c = 0; c < NCHUNK; ++c) {
        // stage chunk c into LDS (in-order DS per wave makes this visible to reads below)
#pragma unroll
        for (int it = 0; it < 7; ++it) ((float*)xw)[loff[it]] = st[it];
        // prefetch chunk c+1 while computing chunk c
        if (c + 1 < NCHUNK) {
#pragma unroll
            for (int it = 0; it < 7; ++it) { st[it] = *gptr[it]; gptr[it] += TC * INPUT; }
        }
        __builtin_amdgcn_wave_barrier();

        // ===== Phase A: batched x-projections for all 16 steps -> registers =====
        v2f xp0[TC], xp1[TC];
#pragma unroll
        for (int t = 0; t < TC; ++t) {
            const float* xrow = &xw[grp][t][0];
            float4 xa = *(const float4*)(xrow + 0);
            float4 xb = *(const float4*)(xrow + 4);
            float4 xc = *(const float4*)(xrow + 8);
            float2 xd = *(const float2*)(xrow + 12);
            v2f a0 = pk_fma((v2f){xa.x, xa.y}, wi1p[0], bias1);
            v2f a1 = pk_mul((v2f){xa.z, xa.w}, wi1p[1]);
            a0 = pk_fma((v2f){xb.x, xb.y}, wi1p[2], a0);
            a1 = pk_fma((v2f){xb.z, xb.w}, wi1p[3], a1);
            a0 = pk_fma((v2f){xc.x, xc.y}, wi1p[4], a0);
            a1 = pk_fma((v2f){xc.z, xc.w}, wi1p[5], a1);
            a0 = pk_fma((v2f){xd.x, xd.y}, wi1p[6], a0);
            xp0[t] = a0;
            xp1[t] = a1;
        }

        // ===== Phase B: skewed recurrence -- body s computes L1(s) and L2(s-1) =====
#pragma unroll
        for (int t = 0; t < TC; ++t) {
            // ---- L1 dot for step s (uses hx1 = h1(s-1) images) ----
            v2f sA = pk_fma(hx1[0], wh1v[0], xp0[t]);
            v2f sB = pk_fma(hx1[1], wh1v[1], xp1[t]);
            sA = pk_fma(hx1[2], wh1v[2], sA);
            sB = pk_fma(hx1[3], wh1v[3], sB);
            v2f sC = pk_add(sA, sB);
            float acc1 = sC.x + sC.y;

            // ---- L2 dot for step s-1 (hx2 = h2(s-2) images; hx1 = h1(s-1) images,
            //      read BEFORE butterfly1 overwrites them) ----
            v2f qA = pk_fma(hx2[0], wh2v[0], bias2);
            v2f qB = pk_mul(hx2[1], wh2v[1]);
            qA = pk_fma(hx2[2], wh2v[2], qA);
            qB = pk_fma(hx2[3], wh2v[3], qB);
            v2f pA = pk_fma(hx1[0], wi2v[0], qA);
            v2f pB = pk_fma(hx1[1], wi2v[1], qB);
            pA = pk_fma(hx1[2], wi2v[2], pA);
            pB = pk_fma(hx1[3], wi2v[3], pB);
            v2f pC = pk_add(pA, pB);
            float acc2 = pC.x + pC.y;

            // ---- two INDEPENDENT activation chains (compiler interleaves) ----
            float v0 = fmaf(fast_rcp(1.f + fast_exp2(acc1)), actMul, actAdd);
            float u0 = fmaf(fast_rcp(1.f + fast_exp2(acc2)), actMul, actAdd);

            float vi = dpp<DPP_BC0>(v0);
            float vf = dpp<DPP_BC1>(v0);
            float vg = dpp<DPP_BC2>(v0);   // = -2.885*tanh(g)
            float vo = dpp<DPP_BC3>(v0);
            c1 = fmaf(vf, c1, vi * vg);
            float th1 = fmaf(fast_rcp(1.f + fast_exp2(c1)), 2.f, -1.f);
            float h1u = vo * th1;          // h1(s)

            float ui = dpp<DPP_BC0>(u0);
            float uf = dpp<DPP_BC1>(u0);
            float ug = dpp<DPP_BC2>(u0);
            float uo = dpp<DPP_BC3>(u0);
            c2 = fmaf(uf, c2, ui * ug);
            float th2 = fmaf(fast_rcp(1.f + fast_exp2(c2)), 2.f, -1.f);
            float h2u = uo * th2;          // h2(s-1)

            butterfly8v(h1u, hx1);
            butterfly8v(h2u, hx2);

            // first body's L2 output is garbage (h2(-1) must be 0)
            if (c == 0 && t == 0) {
#pragma unroll
                for (int p = 0; p < 4; ++p) hx2[p] = (v2f){0.f, 0.f};
                c2 = 0.f;
            }
        }
    }

    // ---- epilogue drain: L2 for t=511 (hx1 = h1(511), hx2 = h2(510)) ----
    {
        v2f qA = pk_fma(hx2[0], wh2v[0], bias2);
        v2f qB = pk_mul(hx2[1], wh2v[1]);
        qA = pk_fma(hx2[2], wh2v[2], qA);
        qB = pk_fma(hx2[3], wh2v[3], qB);
        v2f pA = pk_fma(hx1[0], wi2v[0], qA);
        v2f pB = pk_fma(hx1[1], wi2v[1], qB);
        pA = pk_fma(hx1[2], wi2v[2], pA);
        pB = pk_fma(hx1[3], wi2v[3], pB);
        v2f pC = pk_add(pA, pB);
        float acc2 = pC.x + pC.y;

        float u0 = fmaf(fast_rcp(1.f + fast_exp2(acc2)), actMul, actAdd);
        float ui = dpp<DPP_BC0>(u0);
        float uf = dpp<DPP_BC1>(u0);
        float ug = dpp<DPP_BC2>(u0);
        float uo = dpp<DPP_BC3>(u0);
        c2 = fmaf(uf, c2, ui * ug);
        float th2 = fmaf(fast_rcp(1.f + fast_exp2(c2)), 2.f, -1.f);
        float h2u = uo * th2;              // h2(511)
        butterfly8v(h2u, hx2);
    }

    // ---- BN (eval) + MLP head, one lane per batch element ----
    // At l5==0 (u==0): pairs hold units {0,2},{1,3},{4,6},{5,7}.
    if (l5 == 0) {
        float h2v[HID];
        h2v[0] = hx2[0].x; h2v[2] = hx2[0].y;
        h2v[1] = hx2[1].x; h2v[3] = hx2[1].y;
        h2v[4] = hx2[2].x; h2v[6] = hx2[2].y;
        h2v[5] = hx2[3].x; h2v[7] = hx2[3].y;
        float nd[HID];
#pragma unroll
        for (int j = 0; j < HID; ++j) {
            float inv = 1.f / sqrtf(bn_var[j] + BN_EPS);
            nd[j] = bn_gamma[j] * (h2v[j] - bn_mean[j]) * inv + bn_beta[j];
        }
        float acc = b2p[0];
#pragma unroll
        for (int m = 0; m < 4; ++m) {
            float s = b1p[m];
#pragma unroll
            for (int j = 0; j < HID; ++j) s = fmaf(nd[j], w1p[m * HID + j], s);
            s = fmaxf(s, 0.f);
            acc = fmaf(s, w2p[m], acc);
        }
        out[b] = acc;
    }
}

extern "C" void kernel_launch(void* const* d_in, const int* in_sizes, int n_in,
                              void* d_out, int out_size, void* d_ws, size_t ws_size,
                              hipStream_t stream) {
    const float* x        = (const float*)d_in[0];
    const float* Wih1     = (const float*)d_in[1];
    const float* Whh1     = (const float*)d_in[2];
    const float* bih1     = (const float*)d_in[3];
    const float* bhh1     = (const float*)d_in[4];
    const float* Wih2     = (const float*)d_in[5];
    const float* Whh2     = (const float*)d_in[6];
    const float* bih2     = (const float*)d_in[7];
    const float* bhh2     = (const float*)d_in[8];
    const float* bn_gamma = (const float*)d_in[9];
    const float* bn_beta  = (const float*)d_in[10];
    const float* bn_mean  = (const float*)d_in[11];
    const float* bn_var   = (const float*)d_in[12];
    const float* w1p      = (const float*)d_in[13];
    const float* b1p      = (const float*)d_in[14];
    const float* w2p      = (const float*)d_in[15];
    const float* b2p      = (const float*)d_in[16];
    float* out = (float*)d_out;

    const int B = in_sizes[0] / (T_SEQ * INPUT);   // 4096
    dim3 grid(B / 8), block(256);
    hipLaunchKernelGGL(lstm_forex_kernel, grid, block, 0, stream,
                       x, Wih1, Whh1, bih1, bhh1, Wih2, Whh2, bih2, bhh2,
                       bn_gamma, bn_beta, bn_mean, bn_var, w1p, b1p, w2p, b2p, out);
}